// Round 9
// baseline (678.915 us; speedup 1.0000x reference)
//
#include <hip/hip_runtime.h>
#include <hip/hip_bf16.h>
#include <math.h>

// Problem constants (fixed by the reference)
#define NN   10000   // nodes
#define EE   160000  // edges
#define WID  256     // node width
#define HIDD 512     // hidden
#define EWID 128     // edge embed width

typedef __attribute__((ext_vector_type(8))) short bf16x8;
typedef __attribute__((ext_vector_type(4))) float f32x4;

__device__ __forceinline__ float geluf(float x) {
    return 0.5f * x * (1.0f + erff(x * 0.70710678118654752f));
}

// fp32 -> bf16 bits, round-to-nearest-even
__device__ __forceinline__ unsigned short f2bf(float f) {
    unsigned int u = __float_as_uint(f);
    u += 0x7fffu + ((u >> 16) & 1u);
    return (unsigned short)(u >> 16);
}

// unpack one half of a packed bf16 pair
__device__ __forceinline__ float bfup(unsigned int u, int hi) {
    return hi ? __uint_as_float(u & 0xffff0000u) : __uint_as_float(u << 16);
}

// ---------------- all weight conversions in one kernel ----------------
__global__ __launch_bounds__(256) void k_cvtall(
    const float* __restrict__ Wr0, const float* __restrict__ Wr1,
    const float* __restrict__ Wr2,
    const float* __restrict__ Wq, const float* __restrict__ Wk,
    const float* __restrict__ Wv, const float* __restrict__ Wm,
    const float* __restrict__ Wpre, const float* __restrict__ Wpost,
    unsigned short* __restrict__ WrT, unsigned short* __restrict__ WTn,
    unsigned short* __restrict__ WpreT, unsigned short* __restrict__ WpostT) {
    int tid = blockIdx.x * 256 + threadIdx.x;
    if (tid < 196608) {
        int p = tid >> 16, rem = tid & 65535;
        int n = rem >> 7, k = rem & 127;
        const float* W = p == 0 ? Wr0 : p == 1 ? Wr1 : Wr2;
        WrT[tid] = f2bf(W[k * HIDD + n]);
    } else if (tid < 720896) {
        int u = tid - 196608;
        int sel = u >> 17, rem = u & 131071;
        int n = rem >> 8, k = rem & 255;
        const float* W = sel == 0 ? Wq : sel == 1 ? Wk : sel == 2 ? Wv : Wm;
        WTn[u] = f2bf(W[k * HIDD + n]);
    } else if (tid < 786432) {
        int u = tid - 720896;
        int n = u >> 8, k = u & 255;
        WpreT[u] = f2bf(Wpre[k * WID + n]);
    } else {
        int u = tid - 786432;
        int n = u >> 9, k = u & 511;
        WpostT[u] = f2bf(Wpost[k * WID + n]);
    }
}

// ---------------- ee build: bf16 A-fragment-ordered edge embeddings ----------------
__global__ __launch_bounds__(256) void k_ee(
    const int* __restrict__ eattr, const float* __restrict__ eemb,
    const float* __restrict__ emb0, const float* __restrict__ emb1,
    const float* __restrict__ emb2, const float* __restrict__ emb3,
    const float* __restrict__ i0e,
    unsigned short* __restrict__ eeF) {
    int c = blockIdx.x * 256 + threadIdx.x;        // 0 .. E*16-1
    int lane6 = c & 63;
    int kb = (c >> 6) & 3;
    int tile = c >> 8;
    int edge = tile * 16 + (lane6 & 15);
    int k0 = kb * 32 + (lane6 >> 4) * 8;
    float ev0 = __expf(i0e[0]), ev1 = __expf(i0e[1]),
          ev2 = __expf(i0e[2]), ev3 = __expf(i0e[3]);
    float rsum = rsqrtf(ev0 + ev1 + ev2 + ev3);
    float xw0 = ev0 * rsum, xw1 = ev1 * rsum, xw2 = ev2 * rsum, xw3 = ev3 * rsum;
    int4 at = *(const int4*)&eattr[edge * 4];
    float t0[8], t1[8], t2[8], t3[8], te[8];
    *(float4*)&t0[0] = *(const float4*)&emb0[at.x * EWID + k0];
    *(float4*)&t0[4] = *(const float4*)&emb0[at.x * EWID + k0 + 4];
    *(float4*)&t1[0] = *(const float4*)&emb1[at.y * EWID + k0];
    *(float4*)&t1[4] = *(const float4*)&emb1[at.y * EWID + k0 + 4];
    *(float4*)&t2[0] = *(const float4*)&emb2[at.z * EWID + k0];
    *(float4*)&t2[4] = *(const float4*)&emb2[at.z * EWID + k0 + 4];
    *(float4*)&t3[0] = *(const float4*)&emb3[at.w * EWID + k0];
    *(float4*)&t3[4] = *(const float4*)&emb3[at.w * EWID + k0 + 4];
    *(float4*)&te[0] = *(const float4*)&eemb[edge * EWID + k0];
    *(float4*)&te[4] = *(const float4*)&eemb[edge * EWID + k0 + 4];
    bf16x8 p;
    #pragma unroll
    for (int j = 0; j < 8; ++j)
        p[j] = (short)f2bf(0.5f * (xw0 * t0[j] + xw1 * t1[j] + xw2 * t2[j]
                                   + xw3 * t3[j] + te[j]));
    *(bf16x8*)&eeF[c * 8] = p;
}

// ---------------- pre (MFMA): xxb = bf16(LN(x @ W_pre + b_pre)) ----------------
__global__ __launch_bounds__(256, 4) void k_pre(const float* __restrict__ x,
                                                const unsigned short* __restrict__ WpreT,
                                                const float* __restrict__ bp,
                                                unsigned short* __restrict__ xxb) {
    __shared__ __align__(16) float ot[16 * 260];   // D staging for LN, pitch 260
    int t = threadIdx.x;
    int lane = t & 63, w = t >> 6;
    int l15 = lane & 15, quad = lane >> 4;
    int r0 = blockIdx.x * 16;
    bf16x8 af[8];
    #pragma unroll
    for (int kb = 0; kb < 8; ++kb) {
        int k0 = kb * 32 + quad * 8;
        float a8[8];
        *(float4*)&a8[0] = *(const float4*)&x[(r0 + l15) * WID + k0];
        *(float4*)&a8[4] = *(const float4*)&x[(r0 + l15) * WID + k0 + 4];
        bf16x8 p;
        #pragma unroll
        for (int j = 0; j < 8; ++j) p[j] = (short)f2bf(a8[j]);
        af[kb] = p;
    }
    #pragma unroll
    for (int tb = 0; tb < 4; ++tb) {
        int c = w * 64 + tb * 16 + l15;
        float bias = bp[c];
        f32x4 acc = {bias, bias, bias, bias};
        #pragma unroll
        for (int kb = 0; kb < 8; ++kb) {
            bf16x8 bfr = *(const bf16x8*)&WpreT[c * WID + kb * 32 + quad * 8];
            acc = __builtin_amdgcn_mfma_f32_16x16x32_bf16(af[kb], bfr, acc, 0, 0, 0);
        }
        #pragma unroll
        for (int r = 0; r < 4; ++r)
            ot[(quad * 4 + r) * 260 + c] = acc[r];
    }
    __syncthreads();
    #pragma unroll
    for (int rr = 0; rr < 4; ++rr) {
        int row = w * 4 + rr;
        float s = 0.f, s2 = 0.f;
        #pragma unroll
        for (int k2 = 0; k2 < 4; ++k2) {
            float v = ot[row * 260 + lane + 64 * k2];
            s += v; s2 += v * v;
        }
        #pragma unroll
        for (int off = 32; off >= 1; off >>= 1) {
            s  += __shfl_xor(s,  off, 64);
            s2 += __shfl_xor(s2, off, 64);
        }
        float m = s * (1.f / WID);
        float rstd = rsqrtf(s2 * (1.f / WID) - m * m + 1e-5f);
        #pragma unroll
        for (int k2 = 0; k2 < 4; ++k2) {
            int c = lane + 64 * k2;
            xxb[(r0 + row) * WID + c] = f2bf((ot[row * 260 + c] - m) * rstd);
        }
    }
}

// ---------------- node QKV + msg0 via MFMA, M=32 ----------------
__global__ __launch_bounds__(256, 4) void k_qkvm(
    const unsigned short* __restrict__ xxb,   // [N][256] bf16
    const unsigned short* __restrict__ WTn,   // [4][512][256] bf16
    const float* __restrict__ bq, const float* __restrict__ bk,
    const float* __restrict__ bv, const float* __restrict__ bm,
    unsigned short* __restrict__ XQp, unsigned short* __restrict__ XKp,
    unsigned short* __restrict__ XVp, float* __restrict__ AG) {
    int t = threadIdx.x;
    int r0 = blockIdx.x * 32;
    int sel = blockIdx.y;
    const float* bsel = sel == 0 ? bq : sel == 1 ? bk : sel == 2 ? bv : bm;
    const unsigned short* Wp = WTn + sel * (HIDD * WID);
    unsigned short* outp = sel == 0 ? XQp : sel == 1 ? XKp : XVp;
    int lane = t & 63, w = t >> 6;
    int l15 = lane & 15, quad = lane >> 4;
    int rA = min(r0 + l15, NN - 1);
    int rB = min(r0 + 16 + l15, NN - 1);
    bf16x8 af0[8], af1[8];
    #pragma unroll
    for (int kb = 0; kb < 8; ++kb) {
        af0[kb] = *(const bf16x8*)&xxb[rA * WID + kb * 32 + quad * 8];
        af1[kb] = *(const bf16x8*)&xxb[rB * WID + kb * 32 + quad * 8];
    }
    #pragma unroll
    for (int tb = 0; tb < 8; ++tb) {
        int c = w * 128 + tb * 16;
        float bias = bsel[c + l15];
        f32x4 acc0 = {bias, bias, bias, bias};
        f32x4 acc1 = {bias, bias, bias, bias};
        #pragma unroll
        for (int kb = 0; kb < 8; ++kb) {
            bf16x8 bfr = *(const bf16x8*)&Wp[(c + l15) * WID + kb * 32 + quad * 8];
            acc0 = __builtin_amdgcn_mfma_f32_16x16x32_bf16(af0[kb], bfr, acc0, 0, 0, 0);
            acc1 = __builtin_amdgcn_mfma_f32_16x16x32_bf16(af1[kb], bfr, acc1, 0, 0, 0);
        }
        if (sel < 3) {
            int base = ((w * 64 + (tb >> 1) * 16 + l15) << 1) + (tb & 1);
            #pragma unroll
            for (int r = 0; r < 4; ++r) {
                int n0 = r0 + quad * 4 + r;
                int n1 = n0 + 16;
                if (n0 < NN) outp[n0 * 512 + base] = f2bf(acc0[r]);
                if (n1 < NN) outp[n1 * 512 + base] = f2bf(acc1[r]);
            }
        } else {
            #pragma unroll
            for (int r = 0; r < 4; ++r) {
                int n0 = r0 + quad * 4 + r;
                int n1 = n0 + 16;
                if (n0 < NN) AG[n0 * HIDD + c + l15] = geluf(acc0[r]);
                if (n1 < NN) AG[n1 * HIDD + c + l15] = geluf(acc1[r]);
            }
        }
    }
}

// ---------------- fused edge kernel: 64-col groups, reg-double-buffered B ----
// grid (8, 2500). launch_bounds(256,7): VGPR allocator cap 73 (actual ~56-64),
// LDS 16 KB -> runtime can co-schedule 8 blocks/CU. B for part p+1 is
// prefetched into registers DURING part p's MFMA/consume, so the
// barrier-to-barrier window contains only LDS writes + LDS-fed MFMA — the
// 200-600 cyc global-load latency overlaps compute instead of serializing.
__global__ __launch_bounds__(256, 7) void k_edge(
    const int* __restrict__ eidx,
    const unsigned short* __restrict__ eeF,   // [E/16][4][64][8] bf16
    const float* __restrict__ i0,
    const unsigned int* __restrict__ XQp, const unsigned int* __restrict__ XKp,
    const unsigned int* __restrict__ XVp,
    const unsigned short* __restrict__ WrT,   // [3][512][128] bf16
    const float* __restrict__ br0, const float* __restrict__ br1,
    const float* __restrict__ br2,
    float* __restrict__ agg) {
    __shared__ __align__(16) unsigned short Bs[1024 * 8];   // 16 KB
    int t = threadIdx.x;
    int lane = t & 63, w = t >> 6;
    int l15 = lane & 15, quad = lane >> 4;
    int cg = blockIdx.x;                     // 64-col group
    int tile = blockIdx.y * 4 + w;
    int e0 = tile * 16;

    float a_sc = i0[0], a_bi = i0[1];
    float s_e = expf(i0[2]), s_v = expf(i0[3]);
    float c_sc = 0.125f * a_sc;

    // staging addresses: thread t copies fragments f = i*256+t (tb=i, kb=w)
    int s_off = (cg * 64 + l15) * 128 + w * 32 + quad * 8;  // ushort offset
    bf16x8* sdst = (bf16x8*)Bs + t;
    const bf16x8* bsr = (const bf16x8*)Bs;

    // ---- prefetch part-0 B into registers (in flight across A/idx loads) ----
    bf16x8 bpre[4];
    #pragma unroll
    for (int i = 0; i < 4; ++i)
        bpre[i] = *(const bf16x8*)&WrT[s_off + i * 2048];

    // ---- A fragments: lane-linear 16B loads, precomputed ----
    bf16x8 af[4];
    #pragma unroll
    for (int kb = 0; kb < 4; ++kb)
        af[kb] = *(const bf16x8*)&eeF[((tile * 4 + kb) * 64 + lane) * 8];

    // ---- edge endpoints for this lane's edges (quad*4+r) ----
    int dn[4], sn[4];
    #pragma unroll
    for (int r = 0; r < 4; ++r) {
        int en = e0 + quad * 4 + r;
        sn[r] = eidx[en];
        dn[r] = eidx[EE + en];
    }

    // ---- prefetch Q and K node gathers (2 dwords per edge each) ----
    unsigned int pq[2][4], pk[2][4];
    #pragma unroll
    for (int a = 0; a < 2; ++a)
        #pragma unroll
        for (int r = 0; r < 4; ++r) {
            pq[a][r] = XQp[dn[r] * 256 + cg * 32 + l15 + a * 16];
            pk[a][r] = XKp[sn[r] * 256 + cg * 32 + l15 + a * 16];
        }

    // ================= part 0: Q =================
    #pragma unroll
    for (int i = 0; i < 4; ++i) sdst[i * 256] = bpre[i];
    __syncthreads();
    // prefetch part-1 B during part-0 compute
    #pragma unroll
    for (int i = 0; i < 4; ++i)
        bpre[i] = *(const bf16x8*)&WrT[65536 + s_off + i * 2048];
    float q[4][4];
    #pragma unroll
    for (int tb = 0; tb < 4; ++tb) {
        float bias = br0[cg * 64 + tb * 16 + l15];
        f32x4 acc = {bias, bias, bias, bias};
        #pragma unroll
        for (int kb = 0; kb < 4; ++kb)
            acc = __builtin_amdgcn_mfma_f32_16x16x32_bf16(af[kb], bsr[tb * 256 + kb * 64 + lane], acc, 0, 0, 0);
        #pragma unroll
        for (int r = 0; r < 4; ++r)
            q[tb][r] = bfup(pq[tb >> 1][r], tb & 1) + s_e * acc[r];
    }
    // prefetch V gathers (in flight across part 1)
    unsigned int pv[2][4];
    #pragma unroll
    for (int a = 0; a < 2; ++a)
        #pragma unroll
        for (int r = 0; r < 4; ++r)
            pv[a][r] = XVp[sn[r] * 256 + cg * 32 + l15 + a * 16];
    __syncthreads();

    // ================= part 1: K + attention =================
    #pragma unroll
    for (int i = 0; i < 4; ++i) sdst[i * 256] = bpre[i];
    __syncthreads();
    // prefetch part-2 B during part-1 compute
    #pragma unroll
    for (int i = 0; i < 4; ++i)
        bpre[i] = *(const bf16x8*)&WrT[131072 + s_off + i * 2048];
    float d[4] = {0.f, 0.f, 0.f, 0.f};
    #pragma unroll
    for (int tb = 0; tb < 4; ++tb) {
        float bias = br1[cg * 64 + tb * 16 + l15];
        f32x4 acc = {bias, bias, bias, bias};
        #pragma unroll
        for (int kb = 0; kb < 4; ++kb)
            acc = __builtin_amdgcn_mfma_f32_16x16x32_bf16(af[kb], bsr[tb * 256 + kb * 64 + lane], acc, 0, 0, 0);
        #pragma unroll
        for (int r = 0; r < 4; ++r) {
            float kv = bfup(pk[tb >> 1][r], tb & 1) + s_e * acc[r];
            d[r] += q[tb][r] * kv;
        }
    }
    float att[4];
    #pragma unroll
    for (int off = 8; off >= 1; off >>= 1)
        #pragma unroll
        for (int r = 0; r < 4; ++r)
            d[r] += __shfl_xor(d[r], off, 64);
    #pragma unroll
    for (int r = 0; r < 4; ++r)
        att[r] = expf(d[r] * c_sc + a_bi);
    __syncthreads();

    // ================= part 2: V + scatter =================
    #pragma unroll
    for (int i = 0; i < 4; ++i) sdst[i * 256] = bpre[i];
    __syncthreads();
    #pragma unroll
    for (int tb = 0; tb < 4; ++tb) {
        float bias = br2[cg * 64 + tb * 16 + l15];
        f32x4 acc = {bias, bias, bias, bias};
        #pragma unroll
        for (int kb = 0; kb < 4; ++kb)
            acc = __builtin_amdgcn_mfma_f32_16x16x32_bf16(af[kb], bsr[tb * 256 + kb * 64 + lane], acc, 0, 0, 0);
        #pragma unroll
        for (int r = 0; r < 4; ++r) {
            float v = geluf(bfup(pv[tb >> 1][r], tb & 1) + s_v * acc[r]);
            atomicAdd(&agg[dn[r] * HIDD + cg * 64 + tb * 16 + l15], v * att[r]);
        }
    }
}

// ---------------- post (MFMA): out = x + agg @ W_post + b_post ----------------
__global__ __launch_bounds__(256, 4) void k_post(const float* __restrict__ x,
    const float* __restrict__ agg,
    const unsigned short* __restrict__ WpT,   // [256][512] bf16
    const float* __restrict__ bp,
    float* __restrict__ out) {
    int t = threadIdx.x;
    int lane = t & 63, w = t >> 6;
    int l15 = lane & 15, quad = lane >> 4;
    int r0 = blockIdx.x * 16;
    bf16x8 af[16];
    #pragma unroll
    for (int kb = 0; kb < 16; ++kb) {
        int k0 = kb * 32 + quad * 8;
        float a8[8];
        *(float4*)&a8[0] = *(const float4*)&agg[(r0 + l15) * HIDD + k0];
        *(float4*)&a8[4] = *(const float4*)&agg[(r0 + l15) * HIDD + k0 + 4];
        bf16x8 p;
        #pragma unroll
        for (int j = 0; j < 8; ++j) p[j] = (short)f2bf(a8[j]);
        af[kb] = p;
    }
    #pragma unroll
    for (int tb = 0; tb < 4; ++tb) {
        int c = w * 64 + tb * 16 + l15;
        float bias = bp[c];
        f32x4 acc = {bias, bias, bias, bias};
        #pragma unroll
        for (int kb = 0; kb < 16; ++kb) {
            bf16x8 bfr = *(const bf16x8*)&WpT[c * HIDD + kb * 32 + quad * 8];
            acc = __builtin_amdgcn_mfma_f32_16x16x32_bf16(af[kb], bfr, acc, 0, 0, 0);
        }
        #pragma unroll
        for (int r = 0; r < 4; ++r) {
            int row = r0 + quad * 4 + r;
            out[row * WID + c] = x[row * WID + c] + acc[r];
        }
    }
}

extern "C" void kernel_launch(void* const* d_in, const int* in_sizes, int n_in,
                              void* d_out, int out_size, void* d_ws, size_t ws_size,
                              hipStream_t stream) {
    const float* x     = (const float*)d_in[0];
    const int*   eidx  = (const int*)  d_in[1];
    const int*   eattr = (const int*)  d_in[2];
    const float* eemb  = (const float*)d_in[3];
    const float* emb0  = (const float*)d_in[4];
    const float* emb1  = (const float*)d_in[5];
    const float* emb2  = (const float*)d_in[6];
    const float* emb3  = (const float*)d_in[7];
    const float* i0e   = (const float*)d_in[8];
    const float* i0    = (const float*)d_in[9];
    const float* Wpre  = (const float*)d_in[10];
    const float* bpre  = (const float*)d_in[11];
    const float* Wm    = (const float*)d_in[12];
    const float* bm    = (const float*)d_in[13];
    const float* Wq    = (const float*)d_in[14];
    const float* bq    = (const float*)d_in[15];
    const float* Wk    = (const float*)d_in[16];
    const float* bk    = (const float*)d_in[17];
    const float* Wv    = (const float*)d_in[18];
    const float* bv    = (const float*)d_in[19];
    const float* Wr0   = (const float*)d_in[20];
    const float* br0   = (const float*)d_in[21];
    const float* Wr1   = (const float*)d_in[22];
    const float* br1   = (const float*)d_in[23];
    const float* Wr2   = (const float*)d_in[24];
    const float* br2   = (const float*)d_in[25];
    const float* Wpost = (const float*)d_in[26];
    const float* bpost = (const float*)d_in[27];

    float* ws  = (float*)d_ws;
    float* agg = ws;                                           // N*512 f32
    unsigned short* xxb    = (unsigned short*)(ws + 5120000);  // N*256 bf16
    unsigned short* XQp    = (unsigned short*)(ws + 6400000);  // N*512 bf16 packed
    unsigned short* XKp    = (unsigned short*)(ws + 8960000);
    unsigned short* XVp    = (unsigned short*)(ws + 11520000);
    unsigned short* WrT    = (unsigned short*)(ws + 14080000); // 3*512*128
    unsigned short* WTn    = (unsigned short*)(ws + 14178304); // 4*512*256
    unsigned short* WpreT  = (unsigned short*)(ws + 14440448); // 256*256
    unsigned short* WpostT = (unsigned short*)(ws + 14473216); // 256*512
    unsigned short* eeF    = (unsigned short*)(ws + 14538752); // E*128 bf16 (41 MB)
    // total ~99.1 MB

    k_cvtall<<<3584, 256, 0, stream>>>(Wr0, Wr1, Wr2, Wq, Wk, Wv, Wm, Wpre, Wpost,
                                       WrT, WTn, WpreT, WpostT);
    k_ee<<<10000, 256, 0, stream>>>(eattr, eemb, emb0, emb1, emb2, emb3, i0e, eeF);
    k_pre<<<625, 256, 0, stream>>>(x, WpreT, bpre, xxb);
    k_qkvm<<<dim3(313, 4), 256, 0, stream>>>(xxb, WTn, bq, bk, bv, bm,
                                             XQp, XKp, XVp, agg);
    k_edge<<<dim3(8, 2500), 256, 0, stream>>>(eidx, eeF, i0,
                                              (const unsigned int*)XQp,
                                              (const unsigned int*)XKp,
                                              (const unsigned int*)XVp,
                                              WrT, br0, br1, br2, agg);
    k_post<<<625, 256, 0, stream>>>(x, agg, WpostT, bpost, (float*)d_out);
}